// Round 6
// baseline (6094.584 us; speedup 1.0000x reference)
//
#include <hip/hip_runtime.h>
#include <cmath>
#include <cstdint>

typedef __bf16 bf16;
typedef __bf16 bf16x8 __attribute__((ext_vector_type(8)));
typedef float f32x4 __attribute__((ext_vector_type(4)));

static __device__ __forceinline__ float gelu_exact(float x) {
    return 0.5f * x * (1.f + erff(x * 0.70710678118654752f));
}

static __device__ __forceinline__ float fast_sigmoid(float x) {
    return __builtin_amdgcn_rcpf(1.f + __expf(-x));
}
static __device__ __forceinline__ float fast_tanh(float x) {
    // tanh(x) = 1 - 2/(exp(2x)+1); saturates correctly at +-inf
    return 1.f - 2.f * __builtin_amdgcn_rcpf(1.f + __expf(2.f * x));
}

// ---------- fp32 -> bf16 convert of x with SAME padding rows (t=-1 and t=2000 zeroed) ----------
__global__ void cvt_xpad_kernel(const float* __restrict__ x, bf16* __restrict__ xp) {
    int idx = blockIdx.x * 256 + threadIdx.x;
    if (idx >= 8 * 2002 * 128) return;
    int c = idx & 127;
    int rest = idx >> 7;            // b*2002 + tp
    int tp = rest % 2002;
    int b = rest / 2002;
    float v = 0.f;
    if (tp >= 1 && tp <= 2000) v = x[(b * 2000 + tp - 1) * 128 + c];
    xp[idx] = (bf16)v;
}

// ---------- generic transpose+convert: in fp32 [R][C] -> out [C][Rpad], zero pad r in [R,Rpad) ----------
template <typename OT>
__global__ void transpose_cvt_kernel(const float* __restrict__ in, OT* __restrict__ out,
                                     int R, int C, int Rpad) {
    __shared__ float tile[32][33];
    int tx = threadIdx.x & 31, ty = threadIdx.x >> 5;   // 32 x 8
    int r0 = blockIdx.y * 32, c0 = blockIdx.x * 32;
    for (int i = ty; i < 32; i += 8) {
        int r = r0 + i, c = c0 + tx;
        tile[i][tx] = (r < R && c < C) ? in[(size_t)r * C + c] : 0.f;
    }
    __syncthreads();
    for (int i = ty; i < 32; i += 8) {
        int c = c0 + i, r = r0 + tx;
        if (c < C && r < Rpad) out[(size_t)c * Rpad + r] = (OT)tile[tx][i];
    }
}

// ---------- transpose + split fp32 -> (hi, lo) bf16 pair: in [R][C] -> out [C][R] ----------
__global__ void transpose_split_kernel(const float* __restrict__ in, bf16* __restrict__ hi,
                                       bf16* __restrict__ lo, int R, int C) {
    __shared__ float tile[32][33];
    int tx = threadIdx.x & 31, ty = threadIdx.x >> 5;
    int r0 = blockIdx.y * 32, c0 = blockIdx.x * 32;
    for (int i = ty; i < 32; i += 8) {
        int r = r0 + i, c = c0 + tx;
        tile[i][tx] = (r < R && c < C) ? in[(size_t)r * C + c] : 0.f;
    }
    __syncthreads();
    for (int i = ty; i < 32; i += 8) {
        int c = c0 + i, r = r0 + tx;
        if (c < C && r < R) {
            float v = tile[tx][i];
            bf16 h = (bf16)v;
            size_t o = (size_t)c * R + r;
            hi[o] = h;
            lo[o] = (bf16)(v - (float)h);
        }
    }
}

// ---------- zero h1 pad row (t=2000 per batch) + persistent-LSTM tagged h exchange buffer ----------
// hbuf: [2 par][8][512] packed (seq<<32 | float_bits); seq 0 == initial h_{-1} = 0
__global__ void zero_aux_kernel(bf16* __restrict__ h1, unsigned long long* __restrict__ hbuf) {
    int idx = blockIdx.x * 256 + threadIdx.x;
    if (idx < 8 * 4096) {
        int b = idx >> 12, n = idx & 4095;
        h1[((size_t)(b * 2001 + 2000)) * 4096 + n] = (bf16)0.f;
    }
    int k = idx - 8 * 4096;
    if (k >= 0 && k < 8192) hbuf[k] = 0ull;
}

// ---------- unified bf16 MFMA GEMM, 128x128 tile, BK=32, 256 thr (4 waves, each 64x64) ----------
// MODE 0: conv1  M=16000(b,t)    K=384  (tap,cin)  N=4096  A=xpad[b][t+tap][c]      out: gelu -> h1 bf16 [b][t][n]
// MODE 1: conv2  M=8000 (b,t')   K=12288(tap,cin)  N=1024  A=h1[b][2t'+tap][c]      out: gelu -> h2T bf16 [b][n][t']
// MODE 2: zin    M=8192 (b,s)    K=1024 (f,pad)    N=2048  A=h2T[b][s][f]           out: +bias -> Zin fp32 [b][s][n]
template <int MODE>
__launch_bounds__(256)
__global__ void gemm_kernel(const bf16* __restrict__ A, const bf16* __restrict__ BT,
                            const float* __restrict__ bias, void* __restrict__ Cout) {
    constexpr int KTOT = (MODE == 0) ? 384 : (MODE == 1) ? 12288 : 1024;
    constexpr int MTOT = (MODE == 0) ? 16000 : (MODE == 1) ? 8000 : 8192;
    __shared__ __align__(16) bf16 As[128 * 32];
    __shared__ __align__(16) bf16 Bs[128 * 32];
    const int tid = threadIdx.x;
    const int lane = tid & 63, wave = tid >> 6;
    const int m0 = blockIdx.y * 128, n0 = blockIdx.x * 128;
    const int wm = (wave >> 1) * 64, wn = (wave & 1) * 64;

    f32x4 acc[4][4];
#pragma unroll
    for (int mi = 0; mi < 4; ++mi)
#pragma unroll
        for (int ni = 0; ni < 4; ++ni) acc[mi][ni] = (f32x4){0.f, 0.f, 0.f, 0.f};

    for (int kt = 0; kt < KTOT / 32; ++kt) {
        const int k0 = kt * 32;
        __syncthreads();
#pragma unroll
        for (int s = 0; s < 2; ++s) {
            int ch = tid + s * 256;          // 512 chunks of 16B = 8KB tile
            int row = ch >> 2;
            int ko = (ch & 3) * 8;
            int m = m0 + row;
            if (m > MTOT - 1) m = MTOT - 1;
            const bf16* ga;
            if (MODE == 0) {
                int b = m / 2000, t = m - b * 2000;
                ga = A + ((size_t)(b * 2002 + t + (k0 >> 7)) * 128 + (k0 & 127) + ko);
            } else if (MODE == 1) {
                int b = m / 1000, t = m - b * 1000;
                ga = A + ((size_t)(b * 2001 + 2 * t + (k0 >> 12)) * 4096 + (k0 & 4095) + ko);
            } else {
                ga = A + ((size_t)m * 1000 + k0 + ko);   // overruns row end by <=24 elems; B rows are zero there
            }
            *(uint4*)&As[ch * 8] = *(const uint4*)ga;
            const bf16* gb = BT + ((size_t)(n0 + row) * KTOT + k0 + ko);
            *(uint4*)&Bs[ch * 8] = *(const uint4*)gb;
        }
        __syncthreads();
        bf16x8 af[4], bfr[4];
#pragma unroll
        for (int i = 0; i < 4; ++i)
            af[i] = *(const bf16x8*)&As[(wm + i * 16 + (lane & 15)) * 32 + (lane >> 4) * 8];
#pragma unroll
        for (int i = 0; i < 4; ++i)
            bfr[i] = *(const bf16x8*)&Bs[(wn + i * 16 + (lane & 15)) * 32 + (lane >> 4) * 8];
#pragma unroll
        for (int mi = 0; mi < 4; ++mi)
#pragma unroll
            for (int ni = 0; ni < 4; ++ni)
                acc[mi][ni] = __builtin_amdgcn_mfma_f32_16x16x32_bf16(af[mi], bfr[ni], acc[mi][ni], 0, 0, 0);
    }

#pragma unroll
    for (int mi = 0; mi < 4; ++mi) {
        int rb = m0 + wm + mi * 16 + (lane >> 4) * 4;
#pragma unroll
        for (int ni = 0; ni < 4; ++ni) {
            int col = n0 + wn + ni * 16 + (lane & 15);
#pragma unroll
            for (int i = 0; i < 4; ++i) {
                int row = rb + i;
                float v = acc[mi][ni][i];
                if (MODE == 0) {
                    float y = gelu_exact(v + bias[col]);
                    int b = row / 2000, t = row - b * 2000;
                    ((bf16*)Cout)[(size_t)(b * 2001 + t) * 4096 + col] = (bf16)y;
                } else if (MODE == 1) {
                    if (row < 8000) {
                        float y = gelu_exact(v + bias[col]);
                        int b = row / 1000, t = row - b * 1000;
                        ((bf16*)Cout)[(size_t)(b * 1024 + col) * 1000 + t] = (bf16)y;
                    }
                } else {
                    ((float*)Cout)[(size_t)row * 2048 + col] = v + bias[col];
                }
            }
        }
    }
}

// ---------- persistent LSTM: 32 wgs, tag-in-data h exchange (2-leg protocol), Wr in registers ----
// wg w owns hidden units [16w, 16w+16). Each wave (= gate) holds its 16 gate-cols of Wr (hi+lo
// bf16) as 32 MFMA B-fragments in VGPRs. h is exchanged as packed (seq<<32 | fp32 bits) via
// relaxed agent-scope 8B atomic STORES (no RMW, no drain, no flags, no fences): the consumer's
// poll returns the data itself. Polls are paced with s_sleep to avoid L3 contention (round-4 fix).
// Parity double-buffer + exact-tag matching is ABA-free (see proof in session notes, verified r4).
__launch_bounds__(256, 1)
__global__ void lstm_persist_kernel(const float* __restrict__ Zin,
                                    const bf16* __restrict__ WrHi,
                                    const bf16* __restrict__ WrLo,
                                    unsigned long long* __restrict__ hbuf,
                                    float* __restrict__ out) {
    __shared__ __align__(16) unsigned char hS[2][8192];    // [plane][8 rows x 512 k] bf16, XOR-swizzled
    __shared__ float zex[4][128];                          // [gate][b*16+u]
    const int tid = threadIdx.x;
    const int wv = tid >> 6;          // wave == gate
    const int w = blockIdx.x;
    const int lane = tid & 63;

    // ---- one-time: Wr B-fragments into registers (16 cols x 512 k x hi/lo = 128 VGPRs) ----
    bf16x8 bh[16], bl[16];
    {
        const size_t cb = (size_t)(wv * 512 + w * 16 + (lane & 15)) * 512 + (lane >> 4) * 8;
#pragma unroll
        for (int kk = 0; kk < 16; ++kk) {
            bh[kk] = *(const bf16x8*)&WrHi[cb + kk * 32];
            bl[kk] = *(const bf16x8*)&WrLo[cb + kk * 32];
        }
    }

    const int b = tid >> 4, u = tid & 15, j = w * 16 + u;  // epilogue mapping (tid<128)
    float c_state = 0.f;
    float zin0 = 0.f, zin1 = 0.f, zin2 = 0.f, zin3 = 0.f;
    const float invf = powf(10000.f, -(float)(2 * (j >> 1)) * (1.f / 512.f));
    if (tid < 128) {
        const float* zp = Zin + (size_t)(b * 1024) * 2048;
        zin0 = zp[j]; zin1 = zp[512 + j]; zin2 = zp[1024 + j]; zin3 = zp[1536 + j];
    }

    const int rowsel = lane & 15;       // C col (unit), and A row via &7
    const int kq = lane >> 4;           // k quarter
    const unsigned aswz = (unsigned)((rowsel & 7) << 4);
    const unsigned abase = (unsigned)((rowsel & 7) * 1024);

    // staging indices: thread (srow, scol) reads units [16*scol, 16*scol+16) of batch srow
    const int srow = tid >> 5;
    const int scol = tid & 31;
    const unsigned ssw = (unsigned)((srow & 7) << 4);
    const unsigned sbase = (unsigned)(srow * 1024);

    for (int t = 0; t < 1024; ++t) {
        const int par = t & 1;
        // stage h_{t-1}: poll own 16 packed (seq|val) atoms until seq == t; poll result IS the data
        {
            const unsigned long long* src = hbuf + par * 4096 + srow * 512 + scol * 16;
            unsigned long long pv[16];
            const unsigned tag = (unsigned)t;
            for (;;) {
                bool ok = true;
#pragma unroll
                for (int i = 0; i < 16; ++i) {
                    pv[i] = __hip_atomic_load(&src[i], __ATOMIC_RELAXED, __HIP_MEMORY_SCOPE_AGENT);
                    ok = ok && ((unsigned)(pv[i] >> 32) == tag);
                }
                if (ok) break;
                __builtin_amdgcn_s_sleep(1);   // pace retries: avoid L3 poll flood (r4 lesson)
            }
            float v[16];
#pragma unroll
            for (int i = 0; i < 16; ++i) v[i] = __uint_as_float((unsigned)pv[i]);
            bf16x8 hi0, hi1, lo0, lo1;
#pragma unroll
            for (int i = 0; i < 8; ++i) {
                bf16 h0 = (bf16)v[i];
                hi0[i] = h0; lo0[i] = (bf16)(v[i] - (float)h0);
                bf16 h1 = (bf16)v[8 + i];
                hi1[i] = h1; lo1[i] = (bf16)(v[8 + i] - (float)h1);
            }
            unsigned o0 = (unsigned)(scol * 32);
            *(bf16x8*)&hS[0][sbase + (o0 ^ ssw)] = hi0;
            *(bf16x8*)&hS[0][sbase + ((o0 + 16) ^ ssw)] = hi1;
            *(bf16x8*)&hS[1][sbase + (o0 ^ ssw)] = lo0;
            *(bf16x8*)&hS[1][sbase + ((o0 + 16) ^ ssw)] = lo1;
        }
        __syncthreads();   // S1: hS ready
        // z-tile for gate wv: 16 k-steps x 3 products (hh, lh, hl); B operands from registers
        f32x4 acc0 = {0.f, 0.f, 0.f, 0.f}, acc1 = {0.f, 0.f, 0.f, 0.f}, acc2 = {0.f, 0.f, 0.f, 0.f};
#pragma unroll
        for (int kk = 0; kk < 16; ++kk) {
            unsigned ko = (unsigned)((kk * 4 + kq) * 16);
            bf16x8 ah = *(const bf16x8*)&hS[0][abase + (ko ^ aswz)];
            bf16x8 al = *(const bf16x8*)&hS[1][abase + (ko ^ aswz)];
            acc0 = __builtin_amdgcn_mfma_f32_16x16x32_bf16(ah, bh[kk], acc0, 0, 0, 0);
            acc1 = __builtin_amdgcn_mfma_f32_16x16x32_bf16(al, bh[kk], acc1, 0, 0, 0);
            acc2 = __builtin_amdgcn_mfma_f32_16x16x32_bf16(ah, bl[kk], acc2, 0, 0, 0);
        }
        if (kq < 2) {   // valid batch rows 0..7
#pragma unroll
            for (int i = 0; i < 4; ++i)
                zex[wv][(kq * 4 + i) * 16 + rowsel] = acc0[i] + acc1[i] + acc2[i];
        }
        __syncthreads();   // S2: zex ready, all hS reads of this step complete
        if (tid < 128) {
            float zi = zex[0][tid] + zin0;
            float zf = zex[1][tid] + zin1;
            float zg = zex[2][tid] + zin2;
            float zo = zex[3][tid] + zin3;
            float ig = fast_sigmoid(zi);
            float fg = fast_sigmoid(zf);
            float og = fast_sigmoid(zo);
            float c = fg * c_state + ig * fast_tanh(zg);
            c_state = c;
            float hval = og * fast_tanh(c);
            if (t < 1023) {
                // one atom carries value + readiness; plain atomic store (no RMW), no drain
                unsigned long long pk = ((unsigned long long)(unsigned)(t + 1) << 32) |
                                        (unsigned long long)__float_as_uint(hval);
                __hip_atomic_store(&hbuf[(par ^ 1) * 4096 + b * 512 + j], pk,
                                   __ATOMIC_RELAXED, __HIP_MEMORY_SCOPE_AGENT);
            }
            float ang = (float)t * invf;
            float pe = (j & 1) ? cosf(ang) : sinf(ang);
            out[(size_t)(b * 1024 + t) * 512 + j] = hval + pe;
            if (t < 1023) {
                const float* zp = Zin + (size_t)(b * 1024 + t + 1) * 2048;
                zin0 = zp[j]; zin1 = zp[512 + j]; zin2 = zp[1024 + j]; zin3 = zp[1536 + j];
            }
        }
        // no trailing barrier, no fence: next step's staging self-synchronizes via tags
    }
}

extern "C" void kernel_launch(void* const* d_in, const int* in_sizes, int n_in,
                              void* d_out, int out_size, void* d_ws, size_t ws_size,
                              hipStream_t stream) {
    const float* x  = (const float*)d_in[0];
    const float* w1 = (const float*)d_in[1];
    const float* b1 = (const float*)d_in[2];
    const float* w2 = (const float*)d_in[3];
    const float* b2 = (const float*)d_in[4];
    const float* wk = (const float*)d_in[5];
    const float* wr = (const float*)d_in[6];
    const float* lb = (const float*)d_in[7];
    float* out = (float*)d_out;

    uint8_t* ws = (uint8_t*)d_ws;
    size_t off = 0;
    auto alloc = [&](size_t bytes) {
        void* p = ws + off;
        off += (bytes + 255) & ~(size_t)255;
        return p;
    };
    bf16* xpad = (bf16*)alloc((size_t)8 * 2002 * 128 * 2);
    bf16* W1T  = (bf16*)alloc((size_t)4096 * 384 * 2);
    bf16* W2T  = (bf16*)alloc((size_t)1024 * 12288 * 2);
    bf16* WkT  = (bf16*)alloc((size_t)2048 * 1024 * 2);
    bf16* WrHi = (bf16*)alloc((size_t)2048 * 512 * 2);
    bf16* WrLo = (bf16*)alloc((size_t)2048 * 512 * 2);
    bf16* h1   = (bf16*)alloc((size_t)8 * 2001 * 4096 * 2);
    bf16* h2T  = (bf16*)alloc((size_t)8 * 1024 * 1000 * 2 + 256);  // +slack for k-tail overread
    float* Zin = (float*)alloc((size_t)8 * 1024 * 2048 * 4);
    unsigned long long* hbuf = (unsigned long long*)alloc((size_t)8192 * 8);  // [2 par][8][512] packed

    cvt_xpad_kernel<<<(8 * 2002 * 128 + 255) / 256, 256, 0, stream>>>(x, xpad);
    transpose_cvt_kernel<bf16><<<dim3(128, 12), 256, 0, stream>>>(w1, W1T, 384, 4096, 384);
    transpose_cvt_kernel<bf16><<<dim3(32, 384), 256, 0, stream>>>(w2, W2T, 12288, 1024, 12288);
    transpose_cvt_kernel<bf16><<<dim3(64, 32), 256, 0, stream>>>(wk, WkT, 1000, 2048, 1024);
    transpose_split_kernel<<<dim3(64, 16), 256, 0, stream>>>(wr, WrHi, WrLo, 512, 2048);
    zero_aux_kernel<<<(8 * 4096 + 8192 + 255) / 256, 256, 0, stream>>>(h1, hbuf);

    gemm_kernel<0><<<dim3(32, 125), 256, 0, stream>>>(xpad, W1T, b1, (void*)h1);
    gemm_kernel<1><<<dim3(8, 63), 256, 0, stream>>>(h1, W2T, b2, (void*)h2T);
    gemm_kernel<2><<<dim3(16, 64), 256, 0, stream>>>(h2T, WkT, lb, (void*)Zin);

    lstm_persist_kernel<<<32, 256, 0, stream>>>(Zin, WrHi, WrLo, hbuf, out);
}

// Round 7
// 5043.600 us; speedup vs baseline: 1.2084x; 1.2084x over previous
//
#include <hip/hip_runtime.h>
#include <cmath>
#include <cstdint>

typedef __bf16 bf16;
typedef __bf16 bf16x8 __attribute__((ext_vector_type(8)));
typedef float f32x4 __attribute__((ext_vector_type(4)));

static __device__ __forceinline__ float gelu_exact(float x) {
    return 0.5f * x * (1.f + erff(x * 0.70710678118654752f));
}

static __device__ __forceinline__ float fast_sigmoid(float x) {
    return __builtin_amdgcn_rcpf(1.f + __expf(-x));
}
static __device__ __forceinline__ float fast_tanh(float x) {
    // tanh(x) = 1 - 2/(exp(2x)+1); saturates correctly at +-inf
    return 1.f - 2.f * __builtin_amdgcn_rcpf(1.f + __expf(2.f * x));
}

// ---------- fp32 -> bf16 convert of x with SAME padding rows (t=-1 and t=2000 zeroed) ----------
__global__ void cvt_xpad_kernel(const float* __restrict__ x, bf16* __restrict__ xp) {
    int idx = blockIdx.x * 256 + threadIdx.x;
    if (idx >= 8 * 2002 * 128) return;
    int c = idx & 127;
    int rest = idx >> 7;            // b*2002 + tp
    int tp = rest % 2002;
    int b = rest / 2002;
    float v = 0.f;
    if (tp >= 1 && tp <= 2000) v = x[(b * 2000 + tp - 1) * 128 + c];
    xp[idx] = (bf16)v;
}

// ---------- generic transpose+convert: in fp32 [R][C] -> out [C][Rpad], zero pad r in [R,Rpad) ----------
template <typename OT>
__global__ void transpose_cvt_kernel(const float* __restrict__ in, OT* __restrict__ out,
                                     int R, int C, int Rpad) {
    __shared__ float tile[32][33];
    int tx = threadIdx.x & 31, ty = threadIdx.x >> 5;   // 32 x 8
    int r0 = blockIdx.y * 32, c0 = blockIdx.x * 32;
    for (int i = ty; i < 32; i += 8) {
        int r = r0 + i, c = c0 + tx;
        tile[i][tx] = (r < R && c < C) ? in[(size_t)r * C + c] : 0.f;
    }
    __syncthreads();
    for (int i = ty; i < 32; i += 8) {
        int c = c0 + i, r = r0 + tx;
        if (c < C && r < Rpad) out[(size_t)c * Rpad + r] = (OT)tile[tx][i];
    }
}

// ---------- transpose + split fp32 -> (hi, lo) bf16 pair: in [R][C] -> out [C][R] ----------
__global__ void transpose_split_kernel(const float* __restrict__ in, bf16* __restrict__ hi,
                                       bf16* __restrict__ lo, int R, int C) {
    __shared__ float tile[32][33];
    int tx = threadIdx.x & 31, ty = threadIdx.x >> 5;
    int r0 = blockIdx.y * 32, c0 = blockIdx.x * 32;
    for (int i = ty; i < 32; i += 8) {
        int r = r0 + i, c = c0 + tx;
        tile[i][tx] = (r < R && c < C) ? in[(size_t)r * C + c] : 0.f;
    }
    __syncthreads();
    for (int i = ty; i < 32; i += 8) {
        int c = c0 + i, r = r0 + tx;
        if (c < C && r < R) {
            float v = tile[tx][i];
            bf16 h = (bf16)v;
            size_t o = (size_t)c * R + r;
            hi[o] = h;
            lo[o] = (bf16)(v - (float)h);
        }
    }
}

// ---------- zero h1 pad row + hbuf (tagged) + padded flags ----------
// hbuf: [2 par][8][512] packed (seq<<32 | float_bits); seq 0 == initial h_{-1} = 0
// flagsP: 64 flags, each padded to its own 128B line (stride 32 u32)
__global__ void zero_aux_kernel(bf16* __restrict__ h1, unsigned long long* __restrict__ hbuf,
                                unsigned int* __restrict__ flagsP) {
    int idx = blockIdx.x * 256 + threadIdx.x;
    if (idx < 8 * 4096) {
        int b = idx >> 12, n = idx & 4095;
        h1[((size_t)(b * 2001 + 2000)) * 4096 + n] = (bf16)0.f;
    }
    int k = idx - 8 * 4096;
    if (k >= 0 && k < 8192) hbuf[k] = 0ull;
    int m = k - 8192;
    if (m >= 0 && m < 64 * 32) flagsP[m] = 0u;
}

// ---------- unified bf16 MFMA GEMM, 128x128 tile, BK=32, 256 thr (4 waves, each 64x64) ----------
// MODE 0: conv1  M=16000(b,t)    K=384  (tap,cin)  N=4096  A=xpad[b][t+tap][c]      out: gelu -> h1 bf16 [b][t][n]
// MODE 1: conv2  M=8000 (b,t')   K=12288(tap,cin)  N=1024  A=h1[b][2t'+tap][c]      out: gelu -> h2T bf16 [b][n][t']
// MODE 2: zin    M=8192 (b,s)    K=1024 (f,pad)    N=2048  A=h2T[b][s][f]           out: +bias -> Zin fp32 [b][s][n]
template <int MODE>
__launch_bounds__(256)
__global__ void gemm_kernel(const bf16* __restrict__ A, const bf16* __restrict__ BT,
                            const float* __restrict__ bias, void* __restrict__ Cout) {
    constexpr int KTOT = (MODE == 0) ? 384 : (MODE == 1) ? 12288 : 1024;
    constexpr int MTOT = (MODE == 0) ? 16000 : (MODE == 1) ? 8000 : 8192;
    __shared__ __align__(16) bf16 As[128 * 32];
    __shared__ __align__(16) bf16 Bs[128 * 32];
    const int tid = threadIdx.x;
    const int lane = tid & 63, wave = tid >> 6;
    const int m0 = blockIdx.y * 128, n0 = blockIdx.x * 128;
    const int wm = (wave >> 1) * 64, wn = (wave & 1) * 64;

    f32x4 acc[4][4];
#pragma unroll
    for (int mi = 0; mi < 4; ++mi)
#pragma unroll
        for (int ni = 0; ni < 4; ++ni) acc[mi][ni] = (f32x4){0.f, 0.f, 0.f, 0.f};

    for (int kt = 0; kt < KTOT / 32; ++kt) {
        const int k0 = kt * 32;
        __syncthreads();
#pragma unroll
        for (int s = 0; s < 2; ++s) {
            int ch = tid + s * 256;          // 512 chunks of 16B = 8KB tile
            int row = ch >> 2;
            int ko = (ch & 3) * 8;
            int m = m0 + row;
            if (m > MTOT - 1) m = MTOT - 1;
            const bf16* ga;
            if (MODE == 0) {
                int b = m / 2000, t = m - b * 2000;
                ga = A + ((size_t)(b * 2002 + t + (k0 >> 7)) * 128 + (k0 & 127) + ko);
            } else if (MODE == 1) {
                int b = m / 1000, t = m - b * 1000;
                ga = A + ((size_t)(b * 2001 + 2 * t + (k0 >> 12)) * 4096 + (k0 & 4095) + ko);
            } else {
                ga = A + ((size_t)m * 1000 + k0 + ko);   // overruns row end by <=24 elems; B rows are zero there
            }
            *(uint4*)&As[ch * 8] = *(const uint4*)ga;
            const bf16* gb = BT + ((size_t)(n0 + row) * KTOT + k0 + ko);
            *(uint4*)&Bs[ch * 8] = *(const uint4*)gb;
        }
        __syncthreads();
        bf16x8 af[4], bfr[4];
#pragma unroll
        for (int i = 0; i < 4; ++i)
            af[i] = *(const bf16x8*)&As[(wm + i * 16 + (lane & 15)) * 32 + (lane >> 4) * 8];
#pragma unroll
        for (int i = 0; i < 4; ++i)
            bfr[i] = *(const bf16x8*)&Bs[(wn + i * 16 + (lane & 15)) * 32 + (lane >> 4) * 8];
#pragma unroll
        for (int mi = 0; mi < 4; ++mi)
#pragma unroll
            for (int ni = 0; ni < 4; ++ni)
                acc[mi][ni] = __builtin_amdgcn_mfma_f32_16x16x32_bf16(af[mi], bfr[ni], acc[mi][ni], 0, 0, 0);
    }

#pragma unroll
    for (int mi = 0; mi < 4; ++mi) {
        int rb = m0 + wm + mi * 16 + (lane >> 4) * 4;
#pragma unroll
        for (int ni = 0; ni < 4; ++ni) {
            int col = n0 + wn + ni * 16 + (lane & 15);
#pragma unroll
            for (int i = 0; i < 4; ++i) {
                int row = rb + i;
                float v = acc[mi][ni][i];
                if (MODE == 0) {
                    float y = gelu_exact(v + bias[col]);
                    int b = row / 2000, t = row - b * 2000;
                    ((bf16*)Cout)[(size_t)(b * 2001 + t) * 4096 + col] = (bf16)y;
                } else if (MODE == 1) {
                    if (row < 8000) {
                        float y = gelu_exact(v + bias[col]);
                        int b = row / 1000, t = row - b * 1000;
                        ((bf16*)Cout)[(size_t)(b * 1024 + col) * 1000 + t] = (bf16)y;
                    }
                } else {
                    ((float*)Cout)[(size_t)row * 2048 + col] = v + bias[col];
                }
            }
        }
    }
}

// ---------- persistent LSTM: 32 wgs, tagged data + flag-paced sweeps, Wr in registers ----------
// wg w owns hidden units [16w, 16w+16). Wave (= gate) holds its Wr cols (hi+lo bf16) in VGPRs.
// h exchanged as packed (seq<<32 | fp32 bits) relaxed agent 8B atomic stores (no drain, no RMW).
// Producers fire a per-wave flag immediately (may race ahead of data); wave 3 polls the 64
// LINE-PADDED flags (cheap: 2K loads/retry, no false sharing), barrier releases staging, which
// does ONE tagged sweep and validates per-atom (race window ~ns => retries rare). This keeps
// r6's 2-leg protocol while eliminating the r4/r6 poll flood that congested the coherence point.
__launch_bounds__(256, 1)
__global__ void lstm_persist_kernel(const float* __restrict__ Zin,
                                    const bf16* __restrict__ WrHi,
                                    const bf16* __restrict__ WrLo,
                                    unsigned long long* __restrict__ hbuf,
                                    unsigned int* __restrict__ flagsP,
                                    float* __restrict__ out) {
    __shared__ __align__(16) unsigned char hS[2][8192];    // [plane][8 rows x 512 k] bf16, XOR-swizzled
    __shared__ float zex[4][128];                          // [gate][b*16+u]
    const int tid = threadIdx.x;
    const int wv = tid >> 6;          // wave == gate
    const int w = blockIdx.x;
    const int lane = tid & 63;

    // ---- one-time: Wr B-fragments into registers (16 cols x 512 k x hi/lo = 128 VGPRs) ----
    bf16x8 bh[16], bl[16];
    {
        const size_t cb = (size_t)(wv * 512 + w * 16 + (lane & 15)) * 512 + (lane >> 4) * 8;
#pragma unroll
        for (int kk = 0; kk < 16; ++kk) {
            bh[kk] = *(const bf16x8*)&WrHi[cb + kk * 32];
            bl[kk] = *(const bf16x8*)&WrLo[cb + kk * 32];
        }
    }

    const int b = tid >> 4, u = tid & 15, j = w * 16 + u;  // epilogue mapping (tid<128)
    float c_state = 0.f;
    float zin0 = 0.f, zin1 = 0.f, zin2 = 0.f, zin3 = 0.f;
    const float invf = powf(10000.f, -(float)(2 * (j >> 1)) * (1.f / 512.f));
    if (tid < 128) {
        const float* zp = Zin + (size_t)(b * 1024) * 2048;
        zin0 = zp[j]; zin1 = zp[512 + j]; zin2 = zp[1024 + j]; zin3 = zp[1536 + j];
    }

    const int rowsel = lane & 15;       // C col (unit), and A row via &7
    const int kq = lane >> 4;           // k quarter
    const unsigned aswz = (unsigned)((rowsel & 7) << 4);
    const unsigned abase = (unsigned)((rowsel & 7) * 1024);

    // staging indices: thread (srow, scol) reads units [16*scol, 16*scol+16) of batch srow
    const int srow = tid >> 5;
    const int scol = tid & 31;
    const unsigned ssw = (unsigned)((srow & 7) << 4);
    const unsigned sbase = (unsigned)(srow * 1024);

    for (int t = 0; t < 1024; ++t) {
        const int par = t & 1;
        // pacing: wave 3 polls the 64 padded flags until all >= t, then barrier releases staging
        if (t > 0) {
            if (wv == 3) {
                const unsigned tgt = (unsigned)t;
                for (;;) {
                    unsigned f = __hip_atomic_load(&flagsP[lane * 32], __ATOMIC_RELAXED,
                                                   __HIP_MEMORY_SCOPE_AGENT);
                    if (__all((int)(f >= tgt))) break;
                    __builtin_amdgcn_s_sleep(1);
                }
            }
            __syncthreads();   // S0: data ~visible for everyone
        }
        // stage h_{t-1}: ONE tagged sweep + per-atom validation (retries rare)
        {
            const unsigned long long* src = hbuf + par * 4096 + srow * 512 + scol * 16;
            unsigned long long pv[16];
            const unsigned tag = (unsigned)t;
#pragma unroll
            for (int i = 0; i < 16; ++i)
                pv[i] = __hip_atomic_load(&src[i], __ATOMIC_RELAXED, __HIP_MEMORY_SCOPE_AGENT);
#pragma unroll
            for (int i = 0; i < 16; ++i) {
                while ((unsigned)(pv[i] >> 32) != tag) {
                    __builtin_amdgcn_s_sleep(1);
                    pv[i] = __hip_atomic_load(&src[i], __ATOMIC_RELAXED, __HIP_MEMORY_SCOPE_AGENT);
                }
            }
            float v[16];
#pragma unroll
            for (int i = 0; i < 16; ++i) v[i] = __uint_as_float((unsigned)pv[i]);
            bf16x8 hi0, hi1, lo0, lo1;
#pragma unroll
            for (int i = 0; i < 8; ++i) {
                bf16 h0 = (bf16)v[i];
                hi0[i] = h0; lo0[i] = (bf16)(v[i] - (float)h0);
                bf16 h1 = (bf16)v[8 + i];
                hi1[i] = h1; lo1[i] = (bf16)(v[8 + i] - (float)h1);
            }
            unsigned o0 = (unsigned)(scol * 32);
            *(bf16x8*)&hS[0][sbase + (o0 ^ ssw)] = hi0;
            *(bf16x8*)&hS[0][sbase + ((o0 + 16) ^ ssw)] = hi1;
            *(bf16x8*)&hS[1][sbase + (o0 ^ ssw)] = lo0;
            *(bf16x8*)&hS[1][sbase + ((o0 + 16) ^ ssw)] = lo1;
        }
        __syncthreads();   // S1: hS ready
        // z-tile for gate wv: 16 k-steps x 3 products (hh, lh, hl); B operands from registers
        f32x4 acc0 = {0.f, 0.f, 0.f, 0.f}, acc1 = {0.f, 0.f, 0.f, 0.f}, acc2 = {0.f, 0.f, 0.f, 0.f};
#pragma unroll
        for (int kk = 0; kk < 16; ++kk) {
            unsigned ko = (unsigned)((kk * 4 + kq) * 16);
            bf16x8 ah = *(const bf16x8*)&hS[0][abase + (ko ^ aswz)];
            bf16x8 al = *(const bf16x8*)&hS[1][abase + (ko ^ aswz)];
            acc0 = __builtin_amdgcn_mfma_f32_16x16x32_bf16(ah, bh[kk], acc0, 0, 0, 0);
            acc1 = __builtin_amdgcn_mfma_f32_16x16x32_bf16(al, bh[kk], acc1, 0, 0, 0);
            acc2 = __builtin_amdgcn_mfma_f32_16x16x32_bf16(ah, bl[kk], acc2, 0, 0, 0);
        }
        if (kq < 2) {   // valid batch rows 0..7
#pragma unroll
            for (int i = 0; i < 4; ++i)
                zex[wv][(kq * 4 + i) * 16 + rowsel] = acc0[i] + acc1[i] + acc2[i];
        }
        __syncthreads();   // S2: zex ready, all hS reads of this step complete
        if (tid < 128) {
            float zi = zex[0][tid] + zin0;
            float zf = zex[1][tid] + zin1;
            float zg = zex[2][tid] + zin2;
            float zo = zex[3][tid] + zin3;
            float ig = fast_sigmoid(zi);
            float fg = fast_sigmoid(zf);
            float og = fast_sigmoid(zo);
            float c = fg * c_state + ig * fast_tanh(zg);
            c_state = c;
            float hval = og * fast_tanh(c);
            if (t < 1023) {
                // tagged atom: value + readiness in one store; no drain, no RMW
                unsigned long long pk = ((unsigned long long)(unsigned)(t + 1) << 32) |
                                        (unsigned long long)__float_as_uint(hval);
                __hip_atomic_store(&hbuf[(par ^ 1) * 4096 + b * 512 + j], pk,
                                   __ATOMIC_RELAXED, __HIP_MEMORY_SCOPE_AGENT);
                // pacing flag fired immediately (may race ahead of data; validation handles it)
                if ((tid & 63) == 0)
                    __hip_atomic_store(&flagsP[(w * 2 + wv) * 32], (unsigned)(t + 1),
                                       __ATOMIC_RELAXED, __HIP_MEMORY_SCOPE_AGENT);
            }
            float ang = (float)t * invf;
            float pe = (j & 1) ? cosf(ang) : sinf(ang);
            out[(size_t)(b * 1024 + t) * 512 + j] = hval + pe;
            if (t < 1023) {
                const float* zp = Zin + (size_t)(b * 1024 + t + 1) * 2048;
                zin0 = zp[j]; zin1 = zp[512 + j]; zin2 = zp[1024 + j]; zin3 = zp[1536 + j];
            }
        }
    }
}

extern "C" void kernel_launch(void* const* d_in, const int* in_sizes, int n_in,
                              void* d_out, int out_size, void* d_ws, size_t ws_size,
                              hipStream_t stream) {
    const float* x  = (const float*)d_in[0];
    const float* w1 = (const float*)d_in[1];
    const float* b1 = (const float*)d_in[2];
    const float* w2 = (const float*)d_in[3];
    const float* b2 = (const float*)d_in[4];
    const float* wk = (const float*)d_in[5];
    const float* wr = (const float*)d_in[6];
    const float* lb = (const float*)d_in[7];
    float* out = (float*)d_out;

    uint8_t* ws = (uint8_t*)d_ws;
    size_t off = 0;
    auto alloc = [&](size_t bytes) {
        void* p = ws + off;
        off += (bytes + 255) & ~(size_t)255;
        return p;
    };
    bf16* xpad = (bf16*)alloc((size_t)8 * 2002 * 128 * 2);
    bf16* W1T  = (bf16*)alloc((size_t)4096 * 384 * 2);
    bf16* W2T  = (bf16*)alloc((size_t)1024 * 12288 * 2);
    bf16* WkT  = (bf16*)alloc((size_t)2048 * 1024 * 2);
    bf16* WrHi = (bf16*)alloc((size_t)2048 * 512 * 2);
    bf16* WrLo = (bf16*)alloc((size_t)2048 * 512 * 2);
    bf16* h1   = (bf16*)alloc((size_t)8 * 2001 * 4096 * 2);
    bf16* h2T  = (bf16*)alloc((size_t)8 * 1024 * 1000 * 2 + 256);  // +slack for k-tail overread
    float* Zin = (float*)alloc((size_t)8 * 1024 * 2048 * 4);
    unsigned long long* hbuf = (unsigned long long*)alloc((size_t)8192 * 8);  // [2 par][8][512] packed
    unsigned int* flagsP = (unsigned int*)alloc((size_t)64 * 32 * 4);         // 64 flags, 128B apart

    cvt_xpad_kernel<<<(8 * 2002 * 128 + 255) / 256, 256, 0, stream>>>(x, xpad);
    transpose_cvt_kernel<bf16><<<dim3(128, 12), 256, 0, stream>>>(w1, W1T, 384, 4096, 384);
    transpose_cvt_kernel<bf16><<<dim3(32, 384), 256, 0, stream>>>(w2, W2T, 12288, 1024, 12288);
    transpose_cvt_kernel<bf16><<<dim3(64, 32), 256, 0, stream>>>(wk, WkT, 1000, 2048, 1024);
    transpose_split_kernel<<<dim3(64, 16), 256, 0, stream>>>(wr, WrHi, WrLo, 512, 2048);
    zero_aux_kernel<<<(8 * 4096 + 8192 + 64 * 32 + 255) / 256, 256, 0, stream>>>(h1, hbuf, flagsP);

    gemm_kernel<0><<<dim3(32, 125), 256, 0, stream>>>(xpad, W1T, b1, (void*)h1);
    gemm_kernel<1><<<dim3(8, 63), 256, 0, stream>>>(h1, W2T, b2, (void*)h2T);
    gemm_kernel<2><<<dim3(16, 64), 256, 0, stream>>>(h2T, WkT, lb, (void*)Zin);

    lstm_persist_kernel<<<32, 256, 0, stream>>>(Zin, WrHi, WrLo, hbuf, flagsP, out);
}

// Round 9
// 3758.896 us; speedup vs baseline: 1.6214x; 1.3418x over previous
//
#include <hip/hip_runtime.h>
#include <cmath>
#include <cstdint>

typedef __bf16 bf16;
typedef __bf16 bf16x8 __attribute__((ext_vector_type(8)));
typedef float f32x4 __attribute__((ext_vector_type(4)));

static __device__ __forceinline__ float gelu_exact(float x) {
    return 0.5f * x * (1.f + erff(x * 0.70710678118654752f));
}

static __device__ __forceinline__ float fast_sigmoid(float x) {
    return __builtin_amdgcn_rcpf(1.f + __expf(-x));
}
static __device__ __forceinline__ float fast_tanh(float x) {
    // tanh(x) = 1 - 2/(exp(2x)+1); saturates correctly at +-inf
    return 1.f - 2.f * __builtin_amdgcn_rcpf(1.f + __expf(2.f * x));
}

// ---- device-coherent 16B ops (same sc1 path agent atomics lower to, but 4x wider) ----
static __device__ __forceinline__ void store16_sc1(float* p, f32x4 v) {
    asm volatile("global_store_dwordx4 %0, %1, off sc1" :: "v"(p), "v"(v) : "memory");
}
static __device__ __forceinline__ void load64_sc1(const float* p, f32x4& a, f32x4& b,
                                                  f32x4& c, f32x4& d) {
    asm volatile(
        "global_load_dwordx4 %0, %4, off sc1\n\t"
        "global_load_dwordx4 %1, %4, off offset:16 sc1\n\t"
        "global_load_dwordx4 %2, %4, off offset:32 sc1\n\t"
        "global_load_dwordx4 %3, %4, off offset:48 sc1\n\t"
        "s_waitcnt vmcnt(0)"
        : "=&v"(a), "=&v"(b), "=&v"(c), "=&v"(d)
        : "v"(p) : "memory");
}

// ---------- fp32 -> bf16 convert of x with SAME padding rows (t=-1 and t=2000 zeroed) ----------
__global__ void cvt_xpad_kernel(const float* __restrict__ x, bf16* __restrict__ xp) {
    int idx = blockIdx.x * 256 + threadIdx.x;
    if (idx >= 8 * 2002 * 128) return;
    int c = idx & 127;
    int rest = idx >> 7;            // b*2002 + tp
    int tp = rest % 2002;
    int b = rest / 2002;
    float v = 0.f;
    if (tp >= 1 && tp <= 2000) v = x[(b * 2000 + tp - 1) * 128 + c];
    xp[idx] = (bf16)v;
}

// ---------- generic transpose+convert: in fp32 [R][C] -> out [C][Rpad], zero pad r in [R,Rpad) ----------
template <typename OT>
__global__ void transpose_cvt_kernel(const float* __restrict__ in, OT* __restrict__ out,
                                     int R, int C, int Rpad) {
    __shared__ float tile[32][33];
    int tx = threadIdx.x & 31, ty = threadIdx.x >> 5;   // 32 x 8
    int r0 = blockIdx.y * 32, c0 = blockIdx.x * 32;
    for (int i = ty; i < 32; i += 8) {
        int r = r0 + i, c = c0 + tx;
        tile[i][tx] = (r < R && c < C) ? in[(size_t)r * C + c] : 0.f;
    }
    __syncthreads();
    for (int i = ty; i < 32; i += 8) {
        int c = c0 + i, r = r0 + tx;
        if (c < C && r < Rpad) out[(size_t)c * Rpad + r] = (OT)tile[tx][i];
    }
}

// ---------- transpose + split fp32 -> (hi, lo) bf16 pair: in [R][C] -> out [C][R] ----------
__global__ void transpose_split_kernel(const float* __restrict__ in, bf16* __restrict__ hi,
                                       bf16* __restrict__ lo, int R, int C) {
    __shared__ float tile[32][33];
    int tx = threadIdx.x & 31, ty = threadIdx.x >> 5;
    int r0 = blockIdx.y * 32, c0 = blockIdx.x * 32;
    for (int i = ty; i < 32; i += 8) {
        int r = r0 + i, c = c0 + tx;
        tile[i][tx] = (r < R && c < C) ? in[(size_t)r * C + c] : 0.f;
    }
    __syncthreads();
    for (int i = ty; i < 32; i += 8) {
        int c = c0 + i, r = r0 + tx;
        if (c < C && r < R) {
            float v = tile[tx][i];
            bf16 h = (bf16)v;
            size_t o = (size_t)c * R + r;
            hi[o] = h;
            lo[o] = (bf16)(v - (float)h);
        }
    }
}

// ---------- zero h1 pad row (t=2000 per batch) + padded flags ----------
// flagsP: 64 flags, each on its own 128B line (stride 32 u32). hstep needs NO init (slot-per-step,
// t=0 skips the load entirely; slots 1..1023 are written before ever being read).
__global__ void zero_aux_kernel(bf16* __restrict__ h1, unsigned int* __restrict__ flagsP) {
    int idx = blockIdx.x * 256 + threadIdx.x;
    if (idx < 8 * 4096) {
        int b = idx >> 12, n = idx & 4095;
        h1[((size_t)(b * 2001 + 2000)) * 4096 + n] = (bf16)0.f;
    }
    int m = idx - 8 * 4096;
    if (m >= 0 && m < 64 * 32) flagsP[m] = 0u;
}

// ---------- unified bf16 MFMA GEMM, 128x128 tile, BK=32, 256 thr (4 waves, each 64x64) ----------
// MODE 0: conv1  M=16000(b,t)    K=384  (tap,cin)  N=4096  A=xpad[b][t+tap][c]      out: gelu -> h1 bf16 [b][t][n]
// MODE 1: conv2  M=8000 (b,t')   K=12288(tap,cin)  N=1024  A=h1[b][2t'+tap][c]      out: gelu -> h2T bf16 [b][n][t']
// MODE 2: zin    M=8192 (b,s)    K=1024 (f,pad)    N=2048  A=h2T[b][s][f]           out: +bias -> Zin fp32 [b][s][n]
template <int MODE>
__launch_bounds__(256)
__global__ void gemm_kernel(const bf16* __restrict__ A, const bf16* __restrict__ BT,
                            const float* __restrict__ bias, void* __restrict__ Cout) {
    constexpr int KTOT = (MODE == 0) ? 384 : (MODE == 1) ? 12288 : 1024;
    constexpr int MTOT = (MODE == 0) ? 16000 : (MODE == 1) ? 8000 : 8192;
    __shared__ __align__(16) bf16 As[128 * 32];
    __shared__ __align__(16) bf16 Bs[128 * 32];
    const int tid = threadIdx.x;
    const int lane = tid & 63, wave = tid >> 6;
    const int m0 = blockIdx.y * 128, n0 = blockIdx.x * 128;
    const int wm = (wave >> 1) * 64, wn = (wave & 1) * 64;

    f32x4 acc[4][4];
#pragma unroll
    for (int mi = 0; mi < 4; ++mi)
#pragma unroll
        for (int ni = 0; ni < 4; ++ni) acc[mi][ni] = (f32x4){0.f, 0.f, 0.f, 0.f};

    for (int kt = 0; kt < KTOT / 32; ++kt) {
        const int k0 = kt * 32;
        __syncthreads();
#pragma unroll
        for (int s = 0; s < 2; ++s) {
            int ch = tid + s * 256;          // 512 chunks of 16B = 8KB tile
            int row = ch >> 2;
            int ko = (ch & 3) * 8;
            int m = m0 + row;
            if (m > MTOT - 1) m = MTOT - 1;
            const bf16* ga;
            if (MODE == 0) {
                int b = m / 2000, t = m - b * 2000;
                ga = A + ((size_t)(b * 2002 + t + (k0 >> 7)) * 128 + (k0 & 127) + ko);
            } else if (MODE == 1) {
                int b = m / 1000, t = m - b * 1000;
                ga = A + ((size_t)(b * 2001 + 2 * t + (k0 >> 12)) * 4096 + (k0 & 4095) + ko);
            } else {
                ga = A + ((size_t)m * 1000 + k0 + ko);   // overruns row end by <=24 elems; B rows are zero there
            }
            *(uint4*)&As[ch * 8] = *(const uint4*)ga;
            const bf16* gb = BT + ((size_t)(n0 + row) * KTOT + k0 + ko);
            *(uint4*)&Bs[ch * 8] = *(const uint4*)gb;
        }
        __syncthreads();
        bf16x8 af[4], bfr[4];
#pragma unroll
        for (int i = 0; i < 4; ++i)
            af[i] = *(const bf16x8*)&As[(wm + i * 16 + (lane & 15)) * 32 + (lane >> 4) * 8];
#pragma unroll
        for (int i = 0; i < 4; ++i)
            bfr[i] = *(const bf16x8*)&Bs[(wn + i * 16 + (lane & 15)) * 32 + (lane >> 4) * 8];
#pragma unroll
        for (int mi = 0; mi < 4; ++mi)
#pragma unroll
            for (int ni = 0; ni < 4; ++ni)
                acc[mi][ni] = __builtin_amdgcn_mfma_f32_16x16x32_bf16(af[mi], bfr[ni], acc[mi][ni], 0, 0, 0);
    }

#pragma unroll
    for (int mi = 0; mi < 4; ++mi) {
        int rb = m0 + wm + mi * 16 + (lane >> 4) * 4;
#pragma unroll
        for (int ni = 0; ni < 4; ++ni) {
            int col = n0 + wn + ni * 16 + (lane & 15);
#pragma unroll
            for (int i = 0; i < 4; ++i) {
                int row = rb + i;
                float v = acc[mi][ni][i];
                if (MODE == 0) {
                    float y = gelu_exact(v + bias[col]);
                    int b = row / 2000, t = row - b * 2000;
                    ((bf16*)Cout)[(size_t)(b * 2001 + t) * 4096 + col] = (bf16)y;
                } else if (MODE == 1) {
                    if (row < 8000) {
                        float y = gelu_exact(v + bias[col]);
                        int b = row / 1000, t = row - b * 1000;
                        ((bf16*)Cout)[(size_t)(b * 1024 + col) * 1000 + t] = (bf16)y;
                    }
                } else {
                    ((float*)Cout)[(size_t)row * 2048 + col] = v + bias[col];
                }
            }
        }
    }
}

// ---------- persistent LSTM: 32 wgs, wide-slot exchange (16B sc1), Wr in registers ----------
// wg w owns hidden units [16w, 16w+16). Wave (= gate) holds its Wr cols (hi+lo bf16) in VGPRs.
// h exchanged through hstep[1024][8][512] fp32 (ALIASED onto the dead h1 buffer — h1 is consumed
// by gemm<1> which completes before this kernel launches; saves 16.8MB of workspace): step t
// writes slot t+1, reads slot t — no reuse, no tags, no ABA. Producers shfl-gather 4 values ->
// one 16B sc1 store per 4 lanes, per-wave vmcnt(0) drain, per-wave flag (r5-proven ordering).
// Wave 3 polls 64 line-padded flags; after the barrier every thread pulls its 64B of h via 4
// pipelined 16B sc1 loads (one latency).
__launch_bounds__(256, 1)
__global__ void lstm_persist_kernel(const float* __restrict__ Zin,
                                    const bf16* __restrict__ WrHi,
                                    const bf16* __restrict__ WrLo,
                                    float* __restrict__ hstep,
                                    unsigned int* __restrict__ flagsP,
                                    float* __restrict__ out) {
    __shared__ __align__(16) unsigned char hS[2][8192];    // [plane][8 rows x 512 k] bf16, XOR-swizzled
    __shared__ float zex[4][128];                          // [gate][b*16+u]
    const int tid = threadIdx.x;
    const int wv = tid >> 6;          // wave == gate
    const int w = blockIdx.x;
    const int lane = tid & 63;

    // ---- one-time: Wr B-fragments into registers (16 cols x 512 k x hi/lo = 128 VGPRs) ----
    bf16x8 bh[16], bl[16];
    {
        const size_t cb = (size_t)(wv * 512 + w * 16 + (lane & 15)) * 512 + (lane >> 4) * 8;
#pragma unroll
        for (int kk = 0; kk < 16; ++kk) {
            bh[kk] = *(const bf16x8*)&WrHi[cb + kk * 32];
            bl[kk] = *(const bf16x8*)&WrLo[cb + kk * 32];
        }
    }

    const int b = tid >> 4, u = tid & 15, j = w * 16 + u;  // epilogue mapping (tid<128)
    float c_state = 0.f;
    float zin0 = 0.f, zin1 = 0.f, zin2 = 0.f, zin3 = 0.f;
    const float invf = powf(10000.f, -(float)(2 * (j >> 1)) * (1.f / 512.f));
    if (tid < 128) {
        const float* zp = Zin + (size_t)(b * 1024) * 2048;
        zin0 = zp[j]; zin1 = zp[512 + j]; zin2 = zp[1024 + j]; zin3 = zp[1536 + j];
    }

    const int rowsel = lane & 15;       // C col (unit), and A row via &7
    const int kq = lane >> 4;           // k quarter
    const unsigned aswz = (unsigned)((rowsel & 7) << 4);
    const unsigned abase = (unsigned)((rowsel & 7) * 1024);

    // staging indices: thread (srow, scol) reads units [16*scol, 16*scol+16) of batch srow
    const int srow = tid >> 5;
    const int scol = tid & 31;
    const unsigned ssw = (unsigned)((srow & 7) << 4);
    const unsigned sbase = (unsigned)(srow * 1024);

    for (int t = 0; t < 1024; ++t) {
        // pacing: wave 3 polls the 64 padded flags until all >= t, then barrier releases staging
        if (t > 0) {
            if (wv == 3) {
                const unsigned tgt = (unsigned)t;
                for (;;) {
                    unsigned f = __hip_atomic_load(&flagsP[lane * 32], __ATOMIC_RELAXED,
                                                   __HIP_MEMORY_SCOPE_AGENT);
                    if (__all((int)(f >= tgt))) break;
                    __builtin_amdgcn_s_sleep(1);
                }
            }
            __syncthreads();   // S0: slot t fully written (flags follow per-wave vmcnt drains)
        }
        // stage h_{t-1}: 4 pipelined 16B sc1 loads (one latency), split hi/lo, swizzle into LDS
        {
            float v[16];
            if (t > 0) {
                f32x4 va, vb, vc, vd;
                load64_sc1(hstep + (size_t)t * 4096 + srow * 512 + scol * 16, va, vb, vc, vd);
#pragma unroll
                for (int i = 0; i < 4; ++i) {
                    v[i] = va[i]; v[4 + i] = vb[i]; v[8 + i] = vc[i]; v[12 + i] = vd[i];
                }
            } else {
#pragma unroll
                for (int i = 0; i < 16; ++i) v[i] = 0.f;   // h_{-1} = 0, no load, no init needed
            }
            bf16x8 hi0, hi1, lo0, lo1;
#pragma unroll
            for (int i = 0; i < 8; ++i) {
                bf16 h0 = (bf16)v[i];
                hi0[i] = h0; lo0[i] = (bf16)(v[i] - (float)h0);
                bf16 h1 = (bf16)v[8 + i];
                hi1[i] = h1; lo1[i] = (bf16)(v[8 + i] - (float)h1);
            }
            unsigned o0 = (unsigned)(scol * 32);
            *(bf16x8*)&hS[0][sbase + (o0 ^ ssw)] = hi0;
            *(bf16x8*)&hS[0][sbase + ((o0 + 16) ^ ssw)] = hi1;
            *(bf16x8*)&hS[1][sbase + (o0 ^ ssw)] = lo0;
            *(bf16x8*)&hS[1][sbase + ((o0 + 16) ^ ssw)] = lo1;
        }
        __syncthreads();   // S1: hS ready
        // z-tile for gate wv: 16 k-steps x 3 products (hh, lh, hl); B operands from registers
        f32x4 acc0 = {0.f, 0.f, 0.f, 0.f}, acc1 = {0.f, 0.f, 0.f, 0.f}, acc2 = {0.f, 0.f, 0.f, 0.f};
#pragma unroll
        for (int kk = 0; kk < 16; ++kk) {
            unsigned ko = (unsigned)((kk * 4 + kq) * 16);
            bf16x8 ah = *(const bf16x8*)&hS[0][abase + (ko ^ aswz)];
            bf16x8 al = *(const bf16x8*)&hS[1][abase + (ko ^ aswz)];
            acc0 = __builtin_amdgcn_mfma_f32_16x16x32_bf16(ah, bh[kk], acc0, 0, 0, 0);
            acc1 = __builtin_amdgcn_mfma_f32_16x16x32_bf16(al, bh[kk], acc1, 0, 0, 0);
            acc2 = __builtin_amdgcn_mfma_f32_16x16x32_bf16(ah, bl[kk], acc2, 0, 0, 0);
        }
        if (kq < 2) {   // valid batch rows 0..7
#pragma unroll
            for (int i = 0; i < 4; ++i)
                zex[wv][(kq * 4 + i) * 16 + rowsel] = acc0[i] + acc1[i] + acc2[i];
        }
        __syncthreads();   // S2: zex ready, all hS reads of this step complete
        if (tid < 128) {
            float zi = zex[0][tid] + zin0;
            float zf = zex[1][tid] + zin1;
            float zg = zex[2][tid] + zin2;
            float zo = zex[3][tid] + zin3;
            float ig = fast_sigmoid(zi);
            float fg = fast_sigmoid(zf);
            float og = fast_sigmoid(zo);
            float c = fg * c_state + ig * fast_tanh(zg);
            c_state = c;
            float hval = og * fast_tanh(c);
            if (t < 1023) {
                // gather 4 neighboring units, one 16B device-coherent store per 4 lanes
                float h1s = __shfl_down(hval, 1);
                float h2s = __shfl_down(hval, 2);
                float h3s = __shfl_down(hval, 3);
                if ((tid & 3) == 0) {
                    f32x4 hv = {hval, h1s, h2s, h3s};
                    store16_sc1(hstep + (size_t)(t + 1) * 4096 + b * 512 + j, hv);
                }
                asm volatile("s_waitcnt vmcnt(0)" ::: "memory");   // this wave's stores device-visible
                if (lane == 0)
                    __hip_atomic_store(&flagsP[(w * 2 + wv) * 32], (unsigned)(t + 1),
                                       __ATOMIC_RELAXED, __HIP_MEMORY_SCOPE_AGENT);
            }
            // off-critical-path: output + PE, next-step Zin prefetch
            float ang = (float)t * invf;
            float pe = (j & 1) ? cosf(ang) : sinf(ang);
            out[(size_t)(b * 1024 + t) * 512 + j] = hval + pe;
            if (t < 1023) {
                const float* zp = Zin + (size_t)(b * 1024 + t + 1) * 2048;
                zin0 = zp[j]; zin1 = zp[512 + j]; zin2 = zp[1024 + j]; zin3 = zp[1536 + j];
            }
        }
    }
}

extern "C" void kernel_launch(void* const* d_in, const int* in_sizes, int n_in,
                              void* d_out, int out_size, void* d_ws, size_t ws_size,
                              hipStream_t stream) {
    const float* x  = (const float*)d_in[0];
    const float* w1 = (const float*)d_in[1];
    const float* b1 = (const float*)d_in[2];
    const float* w2 = (const float*)d_in[3];
    const float* b2 = (const float*)d_in[4];
    const float* wk = (const float*)d_in[5];
    const float* wr = (const float*)d_in[6];
    const float* lb = (const float*)d_in[7];
    float* out = (float*)d_out;

    uint8_t* ws = (uint8_t*)d_ws;
    size_t off = 0;
    auto alloc = [&](size_t bytes) {
        void* p = ws + off;
        off += (bytes + 255) & ~(size_t)255;
        return p;
    };
    bf16* xpad = (bf16*)alloc((size_t)8 * 2002 * 128 * 2);
    bf16* W1T  = (bf16*)alloc((size_t)4096 * 384 * 2);
    bf16* W2T  = (bf16*)alloc((size_t)1024 * 12288 * 2);
    bf16* WkT  = (bf16*)alloc((size_t)2048 * 1024 * 2);
    bf16* WrHi = (bf16*)alloc((size_t)2048 * 512 * 2);
    bf16* WrLo = (bf16*)alloc((size_t)2048 * 512 * 2);
    bf16* h1   = (bf16*)alloc((size_t)8 * 2001 * 4096 * 2);
    bf16* h2T  = (bf16*)alloc((size_t)8 * 1024 * 1000 * 2 + 256);  // +slack for k-tail overread
    float* Zin = (float*)alloc((size_t)8 * 1024 * 2048 * 4);
    unsigned int* flagsP = (unsigned int*)alloc((size_t)64 * 32 * 4);  // 64 flags, 128B apart
    // hstep[1024][8][512] fp32 (16.8MB) ALIASED onto h1 (131MB, dead after gemm<1>) — r8's
    // separate allocation overflowed the ~255.5MB workspace and crashed.
    float* hstep = (float*)h1;

    cvt_xpad_kernel<<<(8 * 2002 * 128 + 255) / 256, 256, 0, stream>>>(x, xpad);
    transpose_cvt_kernel<bf16><<<dim3(128, 12), 256, 0, stream>>>(w1, W1T, 384, 4096, 384);
    transpose_cvt_kernel<bf16><<<dim3(32, 384), 256, 0, stream>>>(w2, W2T, 12288, 1024, 12288);
    transpose_cvt_kernel<bf16><<<dim3(64, 32), 256, 0, stream>>>(wk, WkT, 1000, 2048, 1024);
    transpose_split_kernel<<<dim3(64, 16), 256, 0, stream>>>(wr, WrHi, WrLo, 512, 2048);
    zero_aux_kernel<<<(8 * 4096 + 64 * 32 + 255) / 256, 256, 0, stream>>>(h1, flagsP);

    gemm_kernel<0><<<dim3(32, 125), 256, 0, stream>>>(xpad, W1T, b1, (void*)h1);
    gemm_kernel<1><<<dim3(8, 63), 256, 0, stream>>>(h1, W2T, b2, (void*)h2T);
    gemm_kernel<2><<<dim3(16, 64), 256, 0, stream>>>(h2T, WkT, lb, (void*)Zin);

    lstm_persist_kernel<<<32, 256, 0, stream>>>(Zin, WrHi, WrLo, hstep, flagsP, out);
}

// Round 11
// 3256.929 us; speedup vs baseline: 1.8713x; 1.1541x over previous
//
#include <hip/hip_runtime.h>
#include <cmath>
#include <cstdint>

typedef __bf16 bf16;
typedef __bf16 bf16x8 __attribute__((ext_vector_type(8)));
typedef unsigned short u16x8 __attribute__((ext_vector_type(8)));
typedef float f32x4 __attribute__((ext_vector_type(4)));
typedef unsigned u32x4 __attribute__((ext_vector_type(4)));

#define HPOISON 0x7FC07FC0u   // hi-half = bf16 NaN: unreachable for finite h values

static __device__ __forceinline__ float gelu_exact(float x) {
    return 0.5f * x * (1.f + erff(x * 0.70710678118654752f));
}

static __device__ __forceinline__ float fast_sigmoid(float x) {
    return __builtin_amdgcn_rcpf(1.f + __expf(-x));
}
static __device__ __forceinline__ float fast_tanh(float x) {
    // tanh(x) = 1 - 2/(exp(2x)+1); saturates correctly at +-inf
    return 1.f - 2.f * __builtin_amdgcn_rcpf(1.f + __expf(2.f * x));
}

// ---- device-coherent 16B ops (MALL path, proven in r9; ext_vector_type binds to "v") ----
static __device__ __forceinline__ void store16u_sc1(unsigned* p, u32x4 v) {
    asm volatile("global_store_dwordx4 %0, %1, off sc1" :: "v"(p), "v"(v) : "memory");
}
static __device__ __forceinline__ void load64u_sc1(const unsigned* p, u32x4& a, u32x4& b,
                                                   u32x4& c, u32x4& d) {
    asm volatile(
        "global_load_dwordx4 %0, %4, off sc1\n\t"
        "global_load_dwordx4 %1, %4, off offset:16 sc1\n\t"
        "global_load_dwordx4 %2, %4, off offset:32 sc1\n\t"
        "global_load_dwordx4 %3, %4, off offset:48 sc1\n\t"
        "s_waitcnt vmcnt(0)"
        : "=&v"(a), "=&v"(b), "=&v"(c), "=&v"(d)
        : "v"(p) : "memory");
}

// ---------- fp32 -> bf16 convert of x with SAME padding rows (t=-1 and t=2000 zeroed) ----------
__global__ void cvt_xpad_kernel(const float* __restrict__ x, bf16* __restrict__ xp) {
    int idx = blockIdx.x * 256 + threadIdx.x;
    if (idx >= 8 * 2002 * 128) return;
    int c = idx & 127;
    int rest = idx >> 7;            // b*2002 + tp
    int tp = rest % 2002;
    int b = rest / 2002;
    float v = 0.f;
    if (tp >= 1 && tp <= 2000) v = x[(b * 2000 + tp - 1) * 128 + c];
    xp[idx] = (bf16)v;
}

// ---------- generic transpose+convert: in fp32 [R][C] -> out [C][Rpad], zero pad r in [R,Rpad) ----------
template <typename OT>
__global__ void transpose_cvt_kernel(const float* __restrict__ in, OT* __restrict__ out,
                                     int R, int C, int Rpad) {
    __shared__ float tile[32][33];
    int tx = threadIdx.x & 31, ty = threadIdx.x >> 5;   // 32 x 8
    int r0 = blockIdx.y * 32, c0 = blockIdx.x * 32;
    for (int i = ty; i < 32; i += 8) {
        int r = r0 + i, c = c0 + tx;
        tile[i][tx] = (r < R && c < C) ? in[(size_t)r * C + c] : 0.f;
    }
    __syncthreads();
    for (int i = ty; i < 32; i += 8) {
        int c = c0 + i, r = r0 + tx;
        if (c < C && r < Rpad) out[(size_t)c * Rpad + r] = (OT)tile[tx][i];
    }
}

// ---------- transpose + split fp32 -> (hi, lo) bf16 pair: in [R][C] -> out [C][R] ----------
__global__ void transpose_split_kernel(const float* __restrict__ in, bf16* __restrict__ hi,
                                       bf16* __restrict__ lo, int R, int C) {
    __shared__ float tile[32][33];
    int tx = threadIdx.x & 31, ty = threadIdx.x >> 5;
    int r0 = blockIdx.y * 32, c0 = blockIdx.x * 32;
    for (int i = ty; i < 32; i += 8) {
        int r = r0 + i, c = c0 + tx;
        tile[i][tx] = (r < R && c < C) ? in[(size_t)r * C + c] : 0.f;
    }
    __syncthreads();
    for (int i = ty; i < 32; i += 8) {
        int c = c0 + i, r = r0 + tx;
        if (c < C && r < R) {
            float v = tile[tx][i];
            bf16 h = (bf16)v;
            size_t o = (size_t)c * R + r;
            hi[o] = h;
            lo[o] = (bf16)(v - (float)h);
        }
    }
}

// ---------- zero h1 pad row (t=2000 per batch); needed by gemm<1> ----------
__global__ void zero_aux_kernel(bf16* __restrict__ h1) {
    int idx = blockIdx.x * 256 + threadIdx.x;
    if (idx < 8 * 4096) {
        int b = idx >> 12, n = idx & 4095;
        h1[((size_t)(b * 2001 + 2000)) * 4096 + n] = (bf16)0.f;
    }
}

// ---------- poison-fill hstep (runs AFTER gemm<1> frees the aliased h1 region) ----------
// hstep: u32[1024 slots][8][512]; "not yet written" == HPOISON. Slot-per-step => write-once,
// so data self-certifies readiness: no flags, no drains, no ABA.
__global__ void poison_kernel(unsigned* __restrict__ hstep) {
    size_t i = (size_t)blockIdx.x * 256 + threadIdx.x;   // one 16B chunk each
    if (i < (size_t)1024 * 4096 / 4) {
        u32x4 pz = {HPOISON, HPOISON, HPOISON, HPOISON};
        *(u32x4*)(hstep + i * 4) = pz;
    }
}

// ---------- unified bf16 MFMA GEMM, 128x128 tile, BK=32, 256 thr (4 waves, each 64x64) ----------
// MODE 0: conv1  M=16000(b,t)    K=384  (tap,cin)  N=4096  A=xpad[b][t+tap][c]      out: gelu -> h1 bf16 [b][t][n]
// MODE 1: conv2  M=8000 (b,t')   K=12288(tap,cin)  N=1024  A=h1[b][2t'+tap][c]      out: gelu -> h2T bf16 [b][n][t']
// MODE 2: zin    M=8192 (b,s)    K=1024 (f,pad)    N=2048  A=h2T[b][s][f]           out: +bias -> Zin fp32 [b][s][n]
template <int MODE>
__launch_bounds__(256)
__global__ void gemm_kernel(const bf16* __restrict__ A, const bf16* __restrict__ BT,
                            const float* __restrict__ bias, void* __restrict__ Cout) {
    constexpr int KTOT = (MODE == 0) ? 384 : (MODE == 1) ? 12288 : 1024;
    constexpr int MTOT = (MODE == 0) ? 16000 : (MODE == 1) ? 8000 : 8192;
    __shared__ __align__(16) bf16 As[128 * 32];
    __shared__ __align__(16) bf16 Bs[128 * 32];
    const int tid = threadIdx.x;
    const int lane = tid & 63, wave = tid >> 6;
    const int m0 = blockIdx.y * 128, n0 = blockIdx.x * 128;
    const int wm = (wave >> 1) * 64, wn = (wave & 1) * 64;

    f32x4 acc[4][4];
#pragma unroll
    for (int mi = 0; mi < 4; ++mi)
#pragma unroll
        for (int ni = 0; ni < 4; ++ni) acc[mi][ni] = (f32x4){0.f, 0.f, 0.f, 0.f};

    for (int kt = 0; kt < KTOT / 32; ++kt) {
        const int k0 = kt * 32;
        __syncthreads();
#pragma unroll
        for (int s = 0; s < 2; ++s) {
            int ch = tid + s * 256;          // 512 chunks of 16B = 8KB tile
            int row = ch >> 2;
            int ko = (ch & 3) * 8;
            int m = m0 + row;
            if (m > MTOT - 1) m = MTOT - 1;
            const bf16* ga;
            if (MODE == 0) {
                int b = m / 2000, t = m - b * 2000;
                ga = A + ((size_t)(b * 2002 + t + (k0 >> 7)) * 128 + (k0 & 127) + ko);
            } else if (MODE == 1) {
                int b = m / 1000, t = m - b * 1000;
                ga = A + ((size_t)(b * 2001 + 2 * t + (k0 >> 12)) * 4096 + (k0 & 4095) + ko);
            } else {
                ga = A + ((size_t)m * 1000 + k0 + ko);   // overruns row end by <=24 elems; B rows are zero there
            }
            *(uint4*)&As[ch * 8] = *(const uint4*)ga;
            const bf16* gb = BT + ((size_t)(n0 + row) * KTOT + k0 + ko);
            *(uint4*)&Bs[ch * 8] = *(const uint4*)gb;
        }
        __syncthreads();
        bf16x8 af[4], bfr[4];
#pragma unroll
        for (int i = 0; i < 4; ++i)
            af[i] = *(const bf16x8*)&As[(wm + i * 16 + (lane & 15)) * 32 + (lane >> 4) * 8];
#pragma unroll
        for (int i = 0; i < 4; ++i)
            bfr[i] = *(const bf16x8*)&Bs[(wn + i * 16 + (lane & 15)) * 32 + (lane >> 4) * 8];
#pragma unroll
        for (int mi = 0; mi < 4; ++mi)
#pragma unroll
            for (int ni = 0; ni < 4; ++ni)
                acc[mi][ni] = __builtin_amdgcn_mfma_f32_16x16x32_bf16(af[mi], bfr[ni], acc[mi][ni], 0, 0, 0);
    }

#pragma unroll
    for (int mi = 0; mi < 4; ++mi) {
        int rb = m0 + wm + mi * 16 + (lane >> 4) * 4;
#pragma unroll
        for (int ni = 0; ni < 4; ++ni) {
            int col = n0 + wn + ni * 16 + (lane & 15);
#pragma unroll
            for (int i = 0; i < 4; ++i) {
                int row = rb + i;
                float v = acc[mi][ni][i];
                if (MODE == 0) {
                    float y = gelu_exact(v + bias[col]);
                    int b = row / 2000, t = row - b * 2000;
                    ((bf16*)Cout)[(size_t)(b * 2001 + t) * 4096 + col] = (bf16)y;
                } else if (MODE == 1) {
                    if (row < 8000) {
                        float y = gelu_exact(v + bias[col]);
                        int b = row / 1000, t = row - b * 1000;
                        ((bf16*)Cout)[(size_t)(b * 1024 + col) * 1000 + t] = (bf16)y;
                    }
                } else {
                    ((float*)Cout)[(size_t)row * 2048 + col] = v + bias[col];
                }
            }
        }
    }
}

// ---------- persistent LSTM: 32 wgs, self-certifying wide-slot exchange, Wr in registers ----------
// wg w owns hidden units [16w, 16w+16). Wave (= gate) holds its Wr cols (hi+lo bf16) in VGPRs.
// h exchanged through hstep[1024][8][512] u32 = packed (bf16 hi << 16 | bf16 lo) — exactly the
// values the consumer stages, so producer-side splitting is bit-identical. Slot t+1 written at
// step t, read at step t+1; write-once => poison (hi = NaN) means "not yet arrived". Producers:
// pack + shfl-gather 4 -> one 16B sc1 store per 4 lanes, NO drain, NO flag. Consumers: poll own
// 64B (4 pipelined 16B sc1 loads), validate 16 u32 vs poison, paced retry (rare). This deletes
// the r9 chain's drain leg AND the flag indirection leg while keeping the wide-request discipline.
__launch_bounds__(256, 1)
__global__ void lstm_persist_kernel(const float* __restrict__ Zin,
                                    const bf16* __restrict__ WrHi,
                                    const bf16* __restrict__ WrLo,
                                    unsigned* __restrict__ hstep,
                                    float* __restrict__ out) {
    __shared__ __align__(16) unsigned char hS[2][8192];    // [plane][8 rows x 512 k] bf16, XOR-swizzled
    __shared__ float zex[4][128];                          // [gate][b*16+u]
    const int tid = threadIdx.x;
    const int wv = tid >> 6;          // wave == gate
    const int w = blockIdx.x;
    const int lane = tid & 63;

    // ---- one-time: Wr B-fragments into registers (16 cols x 512 k x hi/lo = 128 VGPRs) ----
    bf16x8 bh[16], bl[16];
    {
        const size_t cb = (size_t)(wv * 512 + w * 16 + (lane & 15)) * 512 + (lane >> 4) * 8;
#pragma unroll
        for (int kk = 0; kk < 16; ++kk) {
            bh[kk] = *(const bf16x8*)&WrHi[cb + kk * 32];
            bl[kk] = *(const bf16x8*)&WrLo[cb + kk * 32];
        }
    }

    const int b = tid >> 4, u = tid & 15, j = w * 16 + u;  // epilogue mapping (tid<128)
    float c_state = 0.f;
    float zin0 = 0.f, zin1 = 0.f, zin2 = 0.f, zin3 = 0.f;
    const float invf = powf(10000.f, -(float)(2 * (j >> 1)) * (1.f / 512.f));
    if (tid < 128) {
        const float* zp = Zin + (size_t)(b * 1024) * 2048;
        zin0 = zp[j]; zin1 = zp[512 + j]; zin2 = zp[1024 + j]; zin3 = zp[1536 + j];
    }

    const int rowsel = lane & 15;       // C col (unit), and A row via &7
    const int kq = lane >> 4;           // k quarter
    const unsigned aswz = (unsigned)((rowsel & 7) << 4);
    const unsigned abase = (unsigned)((rowsel & 7) * 1024);

    // staging indices: thread (srow, scol) reads units [16*scol, 16*scol+16) of batch srow
    const int srow = tid >> 5;
    const int scol = tid & 31;
    const unsigned ssw = (unsigned)((srow & 7) << 4);
    const unsigned sbase = (unsigned)(srow * 1024);

    for (int t = 0; t < 1024; ++t) {
        // stage h_{t-1}: poll own 64B until all 16 u32 are non-poison; data IS the readiness
        {
            unsigned vv[16];
            if (t > 0) {
                const unsigned* src = hstep + (size_t)t * 4096 + srow * 512 + scol * 16;
                for (;;) {
                    u32x4 qa, qb, qc, qd;
                    load64u_sc1(src, qa, qb, qc, qd);
#pragma unroll
                    for (int i = 0; i < 4; ++i) {
                        vv[i] = qa[i]; vv[4 + i] = qb[i]; vv[8 + i] = qc[i]; vv[12 + i] = qd[i];
                    }
                    bool ok = true;
#pragma unroll
                    for (int i = 0; i < 16; ++i) ok = ok && (vv[i] != HPOISON);
                    if (ok) break;
                    __builtin_amdgcn_s_sleep(1);   // paced retry; flood-free (32K reqs/sweep max)
                }
            } else {
#pragma unroll
                for (int i = 0; i < 16; ++i) vv[i] = 0u;   // h_{-1} = 0 (bf16 0 bits = 0)
            }
            u16x8 h0, h1v, l0, l1v;
#pragma unroll
            for (int i = 0; i < 8; ++i) {
                h0[i]  = (unsigned short)(vv[i] >> 16);
                l0[i]  = (unsigned short)(vv[i] & 0xFFFFu);
                h1v[i] = (unsigned short)(vv[8 + i] >> 16);
                l1v[i] = (unsigned short)(vv[8 + i] & 0xFFFFu);
            }
            unsigned o0 = (unsigned)(scol * 32);
            *(u16x8*)&hS[0][sbase + (o0 ^ ssw)] = h0;
            *(u16x8*)&hS[0][sbase + ((o0 + 16) ^ ssw)] = h1v;
            *(u16x8*)&hS[1][sbase + (o0 ^ ssw)] = l0;
            *(u16x8*)&hS[1][sbase + ((o0 + 16) ^ ssw)] = l1v;
        }
        __syncthreads();   // S1: hS ready
        // z-tile for gate wv: 16 k-steps x 3 products (hh, lh, hl); B operands from registers
        f32x4 acc0 = {0.f, 0.f, 0.f, 0.f}, acc1 = {0.f, 0.f, 0.f, 0.f}, acc2 = {0.f, 0.f, 0.f, 0.f};
#pragma unroll
        for (int kk = 0; kk < 16; ++kk) {
            unsigned ko = (unsigned)((kk * 4 + kq) * 16);
            bf16x8 ah = *(const bf16x8*)&hS[0][abase + (ko ^ aswz)];
            bf16x8 al = *(const bf16x8*)&hS[1][abase + (ko ^ aswz)];
            acc0 = __builtin_amdgcn_mfma_f32_16x16x32_bf16(ah, bh[kk], acc0, 0, 0, 0);
            acc1 = __builtin_amdgcn_mfma_f32_16x16x32_bf16(al, bh[kk], acc1, 0, 0, 0);
            acc2 = __builtin_amdgcn_mfma_f32_16x16x32_bf16(ah, bl[kk], acc2, 0, 0, 0);
        }
        if (kq < 2) {   // valid batch rows 0..7
#pragma unroll
            for (int i = 0; i < 4; ++i)
                zex[wv][(kq * 4 + i) * 16 + rowsel] = acc0[i] + acc1[i] + acc2[i];
        }
        __syncthreads();   // S2: zex ready, all hS reads of this step complete
        if (tid < 128) {
            float zi = zex[0][tid] + zin0;
            float zf = zex[1][tid] + zin1;
            float zg = zex[2][tid] + zin2;
            float zo = zex[3][tid] + zin3;
            float ig = fast_sigmoid(zi);
            float fg = fast_sigmoid(zf);
            float og = fast_sigmoid(zo);
            float c = fg * c_state + ig * fast_tanh(zg);
            c_state = c;
            float hval = og * fast_tanh(c);
            if (t < 1023) {
                // pack (hi,lo) — bit-identical to consumer-side split of fp32 hval
                bf16 hh = (bf16)hval;
                bf16 hlo = (bf16)(hval - (float)hh);
                unsigned pk = ((unsigned)*(unsigned short*)&hh << 16) |
                              (unsigned)*(unsigned short*)&hlo;
                unsigned p1 = (unsigned)__shfl_down((int)pk, 1);
                unsigned p2 = (unsigned)__shfl_down((int)pk, 2);
                unsigned p3 = (unsigned)__shfl_down((int)pk, 3);
                if ((tid & 3) == 0) {
                    u32x4 hv = {pk, p1, p2, p3};
                    store16u_sc1(hstep + (size_t)(t + 1) * 4096 + b * 512 + j, hv);
                }
                // no drain, no flag: the store itself certifies readiness at the consumer
            }
            // off-critical-path: output + PE, next-step Zin prefetch
            float ang = (float)t * invf;
            float pe = (j & 1) ? cosf(ang) : sinf(ang);
            out[(size_t)(b * 1024 + t) * 512 + j] = hval + pe;
            if (t < 1023) {
                const float* zp = Zin + (size_t)(b * 1024 + t + 1) * 2048;
                zin0 = zp[j]; zin1 = zp[512 + j]; zin2 = zp[1024 + j]; zin3 = zp[1536 + j];
            }
        }
    }
}

extern "C" void kernel_launch(void* const* d_in, const int* in_sizes, int n_in,
                              void* d_out, int out_size, void* d_ws, size_t ws_size,
                              hipStream_t stream) {
    const float* x  = (const float*)d_in[0];
    const float* w1 = (const float*)d_in[1];
    const float* b1 = (const float*)d_in[2];
    const float* w2 = (const float*)d_in[3];
    const float* b2 = (const float*)d_in[4];
    const float* wk = (const float*)d_in[5];
    const float* wr = (const float*)d_in[6];
    const float* lb = (const float*)d_in[7];
    float* out = (float*)d_out;

    uint8_t* ws = (uint8_t*)d_ws;
    size_t off = 0;
    auto alloc = [&](size_t bytes) {
        void* p = ws + off;
        off += (bytes + 255) & ~(size_t)255;
        return p;
    };
    bf16* xpad = (bf16*)alloc((size_t)8 * 2002 * 128 * 2);
    bf16* W1T  = (bf16*)alloc((size_t)4096 * 384 * 2);
    bf16* W2T  = (bf16*)alloc((size_t)1024 * 12288 * 2);
    bf16* WkT  = (bf16*)alloc((size_t)2048 * 1024 * 2);
    bf16* WrHi = (bf16*)alloc((size_t)2048 * 512 * 2);
    bf16* WrLo = (bf16*)alloc((size_t)2048 * 512 * 2);
    bf16* h1   = (bf16*)alloc((size_t)8 * 2001 * 4096 * 2);
    bf16* h2T  = (bf16*)alloc((size_t)8 * 1024 * 1000 * 2 + 256);  // +slack for k-tail overread
    float* Zin = (float*)alloc((size_t)8 * 1024 * 2048 * 4);
    // hstep u32[1024][8][512] (16.8MB) ALIASED onto h1 (131MB, dead after gemm<1>) —
    // a separate allocation would overflow the ~255.5MB workspace (r8 crash).
    unsigned* hstep = (unsigned*)h1;

    cvt_xpad_kernel<<<(8 * 2002 * 128 + 255) / 256, 256, 0, stream>>>(x, xpad);
    transpose_cvt_kernel<bf16><<<dim3(128, 12), 256, 0, stream>>>(w1, W1T, 384, 4096, 384);
    transpose_cvt_kernel<bf16><<<dim3(32, 384), 256, 0, stream>>>(w2, W2T, 12288, 1024, 12288);
    transpose_cvt_kernel<bf16><<<dim3(64, 32), 256, 0, stream>>>(wk, WkT, 1000, 2048, 1024);
    transpose_split_kernel<<<dim3(64, 16), 256, 0, stream>>>(wr, WrHi, WrLo, 512, 2048);
    zero_aux_kernel<<<(8 * 4096 + 255) / 256, 256, 0, stream>>>(h1);

    gemm_kernel<0><<<dim3(32, 125), 256, 0, stream>>>(xpad, W1T, b1, (void*)h1);
    gemm_kernel<1><<<dim3(8, 63), 256, 0, stream>>>(h1, W2T, b2, (void*)h2T);
    // h1 now dead -> poison-fill the aliased hstep slots (off the LSTM critical path)
    poison_kernel<<<4096, 256, 0, stream>>>(hstep);
    gemm_kernel<2><<<dim3(16, 64), 256, 0, stream>>>(h2T, WkT, lb, (void*)Zin);

    lstm_persist_kernel<<<32, 256, 0, stream>>>(Zin, WrHi, WrLo, hstep, out);
}